// Round 15
// baseline (14132.629 us; speedup 1.0000x reference)
//
#include <hip/hip_runtime.h>
#include <cstdint>

using u16 = unsigned short;
using u32 = unsigned int;
using u64 = unsigned long long;

typedef __bf16 bf16x8 __attribute__((ext_vector_type(8)));
typedef float  f32x4  __attribute__((ext_vector_type(4)));
typedef unsigned int u32x4 __attribute__((ext_vector_type(4)));

#define WPITCH 2064
#define SCAN_LDS 156928
#define YG_LDS   147456
#define POLL_BOUND 32768

__device__ __forceinline__ float b2f(u16 u) {
    u32 i = ((u32)u) << 16; float f; __builtin_memcpy(&f, &i, 4); return f;
}
__device__ __forceinline__ u16 f2b(float f) {
    u32 i; __builtin_memcpy(&i, &f, 4);
    u32 r = (i + 0x7FFFu + ((i >> 16) & 1u)) >> 16; return (u16)r;
}
__device__ __forceinline__ uint4 pack8f(const float* f) {
    u16 t[8];
#pragma unroll
    for (int j = 0; j < 8; ++j) t[j] = f2b(f[j]);
    uint4 r; __builtin_memcpy(&r, t, 16); return r;
}

// x-production prefetch register set (all fields statically addressed)
struct XReg { f32x4 a0, a1; u64 v0, v1; f32x4 w0, w1, w2, w3; };

// ---------------------------------------------------------------------------
// Fused 2-layer persistent GRU scan, 512 steps, layer-pipelined (skew 4..8).
// 256 WGs x 512 thr (1 WG/CU): blockIdx>>7 = layer; per layer 4 groups x 32
// WGs; group owns 16 batches, WG owns 32 H-cols. Recurrent weights in VGPRs.
// h0 flows layer0 -> layer1 through a depth-8 bf16 ring in ws (sc0 sc1).
// R15: wave-granular hops — wave wv owns K-chunk [wv*128,+128): it polls
// only its 4 source-WG flags, stages its own 4KB, and enters its GEMV chunk
// with no intervening __syncthreads (barriers remain only at the scZ/tmp16
// reduction fences). Removes 4 barriers/step and decouples wave progress.
// ---------------------------------------------------------------------------
__global__ __launch_bounds__(512) void gru_fused(
    const float* __restrict__ xin,   // input [64][512][1024] f32
    const float* __restrict__ Wxz, const float* __restrict__ Wxr,
    const float* __restrict__ Wxg,
    const float* __restrict__ Whz, const float* __restrict__ Whr,
    const float* __restrict__ Whg,
    const float* __restrict__ bzp, const float* __restrict__ brp,
    const float* __restrict__ bgp,
    float* __restrict__ hout,        // d_out y-region: h1 rows [b][t][1024]
    float* __restrict__ hidden,      // d_out tail [b][2][1024]
    u16* __restrict__ ring,          // [8][64][1024] bf16 (h0 pipe)
    u16* __restrict__ hb,            // [2][4][16][1024] bf16 (h exch, L1 uses)
    u16* __restrict__ rb,            // [2][4][16][1024] bf16 (rh exch)
    u32* __restrict__ flags)         // [2][4][2 phase][512] u32
{
    extern __shared__ char sm[];
    char*  hs    = sm;                     // 33024: h/rh stage, 16 x 2064
    char*  scZ   = sm + 33024;             // 32768: GEMV partials (4 slots)
    char*  xb0   = sm + 65792;             // 16384 each: x-stage buffers
    char*  xb1   = sm + 82176;
    char*  xb2   = sm + 98560;
    char*  xb3   = sm + 114944;            // ends 131328
    float* xls   = (float*)(sm + 131328);  // 24576: [2 buf][2 tl][16 b][96]
    u16*   tmp16 = (u16*)(sm + 155904);    // 1024: publish repack [16][32]

    const int tid   = threadIdx.x;
    const int lane  = tid & 63;
    const int wv    = tid >> 6;
    const int layer = blockIdx.x >> 7;
    const int id    = blockIdx.x & 127;
    const int grp   = id >> 5;
    const int w     = id & 31;
    const int bg0   = grp * 16;
    const int n0w   = w * 32;
    const long wbase = (long)layer * 1048576;
    const long bbase = (long)layer * 1024;

    u16* hbG = hb + (layer * 4 + grp) * 16384;   // [16][1024]
    u16* rbG = rb + (layer * 4 + grp) * 16384;
    u32* f_rh   = flags + ((layer * 4 + grp) * 2 + 0) * 512;
    u32* f_h    = flags + ((layer * 4 + grp) * 2 + 1) * 512;
    u32* f_h_l0 = flags + ((0 * 4 + grp) * 2 + 1) * 512;
    u32* f_h_l1 = flags + ((1 * 4 + grp) * 2 + 1) * 512;

    // ---- recurrent weights -> VGPR B-fragments (k-order matches A-read)
    bf16x8 wZ[2][4], wR[2][4], wG[2][4];
#pragma unroll
    for (int nt = 0; nt < 2; ++nt) {
#pragma unroll
        for (int i = 0; i < 4; ++i) {
            const int k0  = wv * 128 + i * 32 + ((lane >> 4) << 3);
            const int col = n0w + nt * 16 + (lane & 15);
            u16 ez[8], er[8], eg[8];
#pragma unroll
            for (int j = 0; j < 8; ++j) {
                long o = wbase + (long)(k0 + j) * 1024 + col;
                ez[j] = f2b(Whz[o]); er[j] = f2b(Whr[o]); eg[j] = f2b(Whg[o]);
            }
            __builtin_memcpy(&wZ[nt][i], ez, 16);
            __builtin_memcpy(&wR[nt][i], er, 16);
            __builtin_memcpy(&wG[nt][i], eg, 16);
        }
    }

    const int b8  = tid >> 5;           // batch 0..15
    const int n32 = tid & 31;           // col 0..31
    const int ntc = n32 >> 4, nnc = n32 & 15;
    const int ls  = ((b8 >> 2) << 4) | nnc;
    const int el  = b8 & 3;
    const float biasZ = bzp[bbase + n0w + n32];
    const float biasR = brp[bbase + n0w + n32];
    const float biasG = bgp[bbase + n0w + n32];

    // ---- x-production helpers -------------------------------------------
    f32x4 aX0 = {0,0,0,0}, aX1 = {0,0,0,0};
    const int mT0 = (wv < 6) ? 0 : 1, nT0 = (wv < 6) ? wv : wv - 6;
    const int mT1 = 1, nT1 = 2 + wv;    // valid wv<4

    // A-slab: tid in [256,512): u=tid-256; row=u>>3 (0..31); j=u&7 (16B chunk)
    // W-slab: tid in [64,448):  u=tid-64; g3=u>>7; k=(u&127)>>1; half=u&1
    auto XISSUE = [&](int kt, int wt0, XReg& X) {
        if (tid >= 256) {
            int u = tid - 256, r = u >> 3, j = u & 7;
            if (layer == 0) {
                const float* p = xin +
                    ((long)(bg0 + (r & 15)) * 512 + (wt0 + (r >> 4))) * 1024 +
                    kt * 64 + j * 8;
                X.a0 = *(const f32x4*)p;
                X.a1 = *(const f32x4*)(p + 4);
            } else {
                const u64* p = (const u64*)((const char*)ring +
                    ((long)(((wt0 + (r >> 4)) & 7) * 64 + bg0 + (r & 15)) * 1024 +
                     kt * 64 + j * 8) * 2);
                X.v0 = __hip_atomic_load(p, __ATOMIC_RELAXED,
                                         __HIP_MEMORY_SCOPE_AGENT);
                X.v1 = __hip_atomic_load(p + 1, __ATOMIC_RELAXED,
                                         __HIP_MEMORY_SCOPE_AGENT);
            }
        }
        if (tid >= 64 && tid < 448) {
            int u = tid - 64, g3 = u >> 7, rem = u & 127, k = rem >> 1,
                half = rem & 1;
            const float* Wp = (g3 == 0 ? Wxz : (g3 == 1 ? Wxr : Wxg)) + wbase +
                              (long)(kt * 64 + k) * 1024 + n0w + half * 16;
            X.w0 = *(const f32x4*)(Wp);
            X.w1 = *(const f32x4*)(Wp + 4);
            X.w2 = *(const f32x4*)(Wp + 8);
            X.w3 = *(const f32x4*)(Wp + 12);
        }
    };
    auto XSTORE = [&](char* xb, const XReg& X) {
        char* sA = xb; char* sW = xb + 4096;
        if (tid >= 256) {
            int u = tid - 256, r = u >> 3, j = u & 7;
            uint4 val;
            if (layer == 0) {
                float t[8];
                *(f32x4*)t       = X.a0;
                *(f32x4*)(t + 4) = X.a1;
                val = pack8f(t);
            } else {
                __builtin_memcpy(&val, &X.v0, 8);
                __builtin_memcpy(((char*)&val) + 8, &X.v1, 8);
            }
            *(uint4*)(sA + r * 128 + ((j * 16) ^ ((r & 7) << 4))) = val;
        }
        if (tid >= 64 && tid < 448) {
            int u = tid - 64, g3 = u >> 7, rem = u & 127, k = rem >> 1,
                half = rem & 1;
            f32x4 wv4[4] = {X.w0, X.w1, X.w2, X.w3};
#pragma unroll
            for (int c = 0; c < 16; ++c) {
                int row = g3 * 32 + half * 16 + c;
                *(u16*)(sW + row * 128 + ((k * 2) ^ ((row & 7) << 4))) =
                    f2b(wv4[c >> 2][c & 3]);
            }
        }
    };
    auto XMFMA = [&](char* xb) {
        char* sA = xb; char* sW = xb + 4096;
#pragma unroll
        for (int ks = 0; ks < 2; ++ks) {
            int kb = ks * 64 + ((lane >> 4) << 4);
            {
                int ar = mT0 * 16 + (lane & 15), br_ = nT0 * 16 + (lane & 15);
                bf16x8 aF = *(const bf16x8*)(sA + ar * 128 + (kb ^ ((ar & 7) << 4)));
                bf16x8 bF = *(const bf16x8*)(sW + br_ * 128 + (kb ^ ((br_ & 7) << 4)));
                aX0 = __builtin_amdgcn_mfma_f32_16x16x32_bf16(aF, bF, aX0, 0, 0, 0);
            }
            if (wv < 4) {
                int ar = mT1 * 16 + (lane & 15), br_ = nT1 * 16 + (lane & 15);
                bf16x8 aF = *(const bf16x8*)(sA + ar * 128 + (kb ^ ((ar & 7) << 4)));
                bf16x8 bF = *(const bf16x8*)(sW + br_ * 128 + (kb ^ ((br_ & 7) << 4)));
                aX1 = __builtin_amdgcn_mfma_f32_16x16x32_bf16(aF, bF, aX1, 0, 0, 0);
            }
        }
    };
    // consume pre-issued A(kt0),B(kt0+1); issue kt0+2,kt0+3; optional trailing
    // issue (nkt,nkt+1)@nwt0 for the NEXT XP4 call.
    auto XP4 = [&](int kt0, int wt0, XReg& A, XReg& B, int nkt, int nwt0,
                   bool dn) {
        XSTORE(xb0, A);
        XSTORE(xb1, B);
        XISSUE(kt0 + 2, wt0, A);
        XISSUE(kt0 + 3, wt0, B);
        __syncthreads();
        XMFMA(xb0);
        XMFMA(xb1);
        XSTORE(xb2, A);
        XSTORE(xb3, B);
        if (dn) { XISSUE(nkt, nwt0, A); XISSUE(nkt + 1, nwt0, B); }
        __syncthreads();
        XMFMA(xb2);
        XMFMA(xb3);
    };
    auto XWRITE = [&](int buf) {
#pragma unroll
        for (int q = 0; q < 4; ++q) {
            int row = mT0 * 16 + ((lane >> 4) << 2) + q;
            xls[((buf * 2 + mT0) * 16 + (row & 15)) * 96 + nT0 * 16 + (lane & 15)] = aX0[q];
            if (wv < 4) {
                int row1 = 16 + ((lane >> 4) << 2) + q;
                xls[((buf * 2 + 1) * 16 + (row1 & 15)) * 96 + nT1 * 16 + (lane & 15)] = aX1[q];
            }
        }
        aX0 = (f32x4){0,0,0,0}; aX1 = (f32x4){0,0,0,0};
    };
    // ---- wave-granular hop: wave wv polls its 4 source-WG flags, stages
    // its own 4KB k-chunk [wv*128,+128) x 16 batches, no barrier. [R15]
    auto WVSTAGE = [&](const u32* fpbase, u32 tgtv, const char* src) {
        if (lane < 4) {
            const u32* fp = fpbase + (wv * 4 + lane) * 16;
            u32 v; int itc = 0;
            for (;;) {
                asm volatile("global_load_dword %0, %1, off sc0 sc1\n\t"
                             "s_waitcnt vmcnt(0)"
                             : "=v"(v) : "v"(fp) : "memory");
                if (v >= tgtv) break;
                if (++itc > POLL_BOUND) break;   // fail loud, never hang
                __builtin_amdgcn_s_sleep(1);
            }
        }
        __builtin_amdgcn_sched_barrier(0);
        const int colb = wv * 256 + (lane & 15) * 16;
        const char* p0 = src + (long)(lane >> 4) * 2048 + colb;
        const char* p1 = p0 + 4 * 2048;
        const char* p2 = p0 + 8 * 2048;
        const char* p3 = p0 + 12 * 2048;
        u32x4 a0, a1, a2, a3;
        asm volatile(
            "global_load_dwordx4 %0, %4, off sc0 sc1\n\t"
            "global_load_dwordx4 %1, %5, off sc0 sc1\n\t"
            "global_load_dwordx4 %2, %6, off sc0 sc1\n\t"
            "global_load_dwordx4 %3, %7, off sc0 sc1\n\t"
            "s_waitcnt vmcnt(0)"
            : "=&v"(a0), "=&v"(a1), "=&v"(a2), "=&v"(a3)
            : "v"(p0), "v"(p1), "v"(p2), "v"(p3)
            : "memory");
        int b = lane >> 4;
        *(u32x4*)(hs + b * WPITCH + (colb ^ ((b & 7) << 4))) = a0; b += 4;
        *(u32x4*)(hs + b * WPITCH + (colb ^ ((b & 7) << 4))) = a1; b += 4;
        *(u32x4*)(hs + b * WPITCH + (colb ^ ((b & 7) << 4))) = a2; b += 4;
        *(u32x4*)(hs + b * WPITCH + (colb ^ ((b & 7) << 4))) = a3;
    };
    auto PUBLISH = [&](char* dst) {   // [16][1024]bf16 slice from tmp16
        if (tid < 64) {
            int b = tid >> 2, q = tid & 3;
            u16 e[8];
#pragma unroll
            for (int j = 0; j < 8; ++j) e[j] = tmp16[b * 32 + q * 8 + j];
            u32x4 v; __builtin_memcpy(&v, e, 16);
            char* p = dst + b * 2048 + n0w * 2 + q * 16;
            asm volatile("global_store_dwordx4 %0, %1, off sc0 sc1"
                         :: "v"(p), "v"(v) : "memory");
        }
    };
    auto FLAGREL = [&](u32* fp, u32 tgtv) {
        if (tid == 0)
            asm volatile("s_waitcnt vmcnt(0)\n\t"
                         "global_store_dword %0, %1, off sc0 sc1"
                         :: "v"(fp), "v"(tgtv) : "memory");
    };
    auto FLAGWAIT = [&](const u32* fpbase, u32 tgtv) {   // global (early waits)
        if (tid < 32) {
            const u32* fp = fpbase + tid * 16;
            u32 v; int itc = 0;
            for (;;) {
                asm volatile("global_load_dword %0, %1, off sc0 sc1\n\t"
                             "s_waitcnt vmcnt(0)"
                             : "=v"(v) : "v"(fp) : "memory");
                if (v >= tgtv) break;
                if (++itc > POLL_BOUND) break;   // fail loud, never hang
                __builtin_amdgcn_s_sleep(1);
            }
        }
        __builtin_amdgcn_sched_barrier(0);
        __syncthreads();
    };

    // ---- prologue: produce x window [0,1] into xls buf 0.
    // Layer-1 waits f_h_l0 >= 4: covers ring t<=3, including the trailing
    // issue of the step-0 pair (window wt0=2 -> t=2,3).
    XReg A, B;
    {
        if (layer == 1) FLAGWAIT(f_h_l0, 4);
        XISSUE(0, 0, A);
        XISSUE(1, 0, B);
        XP4(0, 0, A, B, 4, 0, true);
        XP4(4, 0, A, B, 8, 0, true);
        XP4(8, 0, A, B, 12, 0, true);
        XP4(12, 0, A, B, 0, 2, true);   // trailing: step-0 XP4a pair @ wt0=2
        __syncthreads();
        XWRITE(0);
        __syncthreads();
    }

    float h_own = 0.f;
    for (int tc = 0; tc < 512; ++tc) {
        const bool prod = (tc < 510);
        const int wt0 = (tc & ~1) + 2;
        const int kb8 = (tc & 1) * 8;
        const int buf = (tc >> 1) & 1;
        const int tl  = tc & 1;

        // ---- layer-0 ring-overwrite throttle (free if on pace)
        if (layer == 0 && tc >= 8)
            FLAGWAIT(f_h_l1, (u32)(tc - 8));    // ring slot tc&7 consumed

        // ---- x-production first half (pair pre-issued at prev step tail)
        if (prod) XP4(kb8 + 0, wt0, A, B, -1, -1, false);

        // ---- h(t-1): wave-granular wait + stage (no barrier) [R15]
        if (tc == 0) {
            const int colb = wv * 256 + (lane & 15) * 16;
#pragma unroll
            for (int ld = 0; ld < 4; ++ld) {
                int b = ld * 4 + (lane >> 4);
                *(u32x4*)(hs + b * WPITCH + (colb ^ ((b & 7) << 4))) =
                    (u32x4){0, 0, 0, 0};
            }
        } else {
            WVSTAGE(f_h, (u32)tc,
                    (layer == 0)
                        ? (const char*)ring + (((tc - 1) & 7) * 64 + bg0) * 2048
                        : (const char*)hbG);
        }

        // ---- z,r GEMV (wave wv consumes its self-staged chunk)
        {
            f32x4 aZ0 = {0,0,0,0}, aZ1 = {0,0,0,0};
            f32x4 aR0 = {0,0,0,0}, aR1 = {0,0,0,0};
#pragma unroll
            for (int i = 0; i < 4; ++i) {
                int kby = wv * 256 + i * 64 + ((lane >> 4) << 4);
                int ar = lane & 15;
                bf16x8 aF = *(const bf16x8*)(hs + ar * WPITCH + (kby ^ ((ar & 7) << 4)));
                aZ0 = __builtin_amdgcn_mfma_f32_16x16x32_bf16(aF, wZ[0][i], aZ0, 0, 0, 0);
                aZ1 = __builtin_amdgcn_mfma_f32_16x16x32_bf16(aF, wZ[1][i], aZ1, 0, 0, 0);
                aR0 = __builtin_amdgcn_mfma_f32_16x16x32_bf16(aF, wR[0][i], aR0, 0, 0, 0);
                aR1 = __builtin_amdgcn_mfma_f32_16x16x32_bf16(aF, wR[1][i], aR1, 0, 0, 0);
            }
            *(f32x4*)(scZ + ((0 * 8 + wv) * 64 + lane) * 16) = aZ0;
            *(f32x4*)(scZ + ((1 * 8 + wv) * 64 + lane) * 16) = aZ1;
            *(f32x4*)(scZ + ((2 * 8 + wv) * 64 + lane) * 16) = aR0;
            *(f32x4*)(scZ + ((3 * 8 + wv) * 64 + lane) * 16) = aR1;
        }
        __syncthreads();

        // ---- z,r reduce (each thread owns (b8,n32) for both gates)
        float zval;
        {
            float sz = 0.f, sr = 0.f;
#pragma unroll
            for (int ww = 0; ww < 8; ++ww) {
                sz += *(const float*)(scZ + (((ntc)     * 8 + ww) * 64 + ls) * 16 + el * 4);
                sr += *(const float*)(scZ + (((2 + ntc) * 8 + ww) * 64 + ls) * 16 + el * 4);
            }
            const float* xrow = xls + ((buf * 2 + tl) * 16 + b8) * 96;
            sz += xrow[n32] + biasZ;
            sr += xrow[32 + n32] + biasR;
            zval = 1.f / (1.f + __expf(-sz));
            float rv = 1.f / (1.f + __expf(-sr));
            tmp16[b8 * 32 + n32] = f2b(rv * h_own);
        }
        __syncthreads();

        PUBLISH((char*)rbG);
        FLAGREL(f_rh + w * 16, (u32)(tc + 1));

        // ---- x-production second half; trailing issue = next step's pair.
        // Before trailing a NEW window (odd tc), layer-1 waits f_h_l0 >=
        // tc+5 so ring t=tc+3,tc+4 are published before the reads issue.
        if (prod) {
            const bool dn  = (tc + 1 < 510);
            if (layer == 1 && tl == 1 && dn)
                FLAGWAIT(f_h_l0, (u32)(tc + 5));
            XISSUE(kb8 + 4, wt0, A);
            XISSUE(kb8 + 5, wt0, B);
            const int nkb  = ((tc + 1) & 1) * 8;
            const int nwt  = ((tc + 1) & ~1) + 2;
            XP4(kb8 + 4, wt0, A, B, nkb, nwt, dn);
        }

        // ---- r*h: wave-granular wait + stage (no barrier) [R15]
        WVSTAGE(f_rh, (u32)(tc + 1), (const char*)rbG);

        // ---- g GEMV
        {
            f32x4 aG0 = {0,0,0,0}, aG1 = {0,0,0,0};
#pragma unroll
            for (int i = 0; i < 4; ++i) {
                int kby = wv * 256 + i * 64 + ((lane >> 4) << 4);
                int ar = lane & 15;
                bf16x8 aF = *(const bf16x8*)(hs + ar * WPITCH + (kby ^ ((ar & 7) << 4)));
                aG0 = __builtin_amdgcn_mfma_f32_16x16x32_bf16(aF, wG[0][i], aG0, 0, 0, 0);
                aG1 = __builtin_amdgcn_mfma_f32_16x16x32_bf16(aF, wG[1][i], aG1, 0, 0, 0);
            }
            *(f32x4*)(scZ + ((0 * 8 + wv) * 64 + lane) * 16) = aG0;
            *(f32x4*)(scZ + ((1 * 8 + wv) * 64 + lane) * 16) = aG1;
        }
        __syncthreads();

        // ---- g reduce + h update
        {
            float sg = 0.f;
#pragma unroll
            for (int ww = 0; ww < 8; ++ww)
                sg += *(const float*)(scZ + ((ntc * 8 + ww) * 64 + ls) * 16 + el * 4);
            sg += xls[((buf * 2 + tl) * 16 + b8) * 96 + 64 + n32] + biasG;
            float e  = __expf(-2.f * sg);
            float gt = 2.f / (1.f + e) - 1.f;
            float hn = zval * h_own + (1.f - zval) * gt;
            h_own = hn;
            tmp16[b8 * 32 + n32] = f2b(hn);
            if (layer == 1)
                hout[((long)(bg0 + b8) * 512 + tc) * 1024 + n0w + n32] = hn;
            if (tc == 511)
                hidden[(long)(bg0 + b8) * 2048 + layer * 1024 + n0w + n32] = hn;
        }
        __syncthreads();

        PUBLISH(layer == 0
                    ? (char*)ring + (((tc & 7) * 64 + bg0) * 2048)
                    : (char*)hbG);
        FLAGREL(f_h + w * 16, (u32)(tc + 1));

        if (tl == 1 && prod) {
            __syncthreads();
            XWRITE(buf ^ 1);
        }
    }
}

// ---------------------------------------------------------------------------
// In-place output projection: y = h1 @ Why + by over h1 rows in d_out.
// ---------------------------------------------------------------------------
__global__ __launch_bounds__(256) void ygemm(const float* __restrict__ Why,
                                             const float* __restrict__ by,
                                             float* __restrict__ y)
{
    extern __shared__ char sm[];
    char* sA = sm;            // 64 rows x 2048B (bf16 k=1024)
    char* sW = sm + 131072;   // 128 n-rows x 128B

    const int tid  = threadIdx.x;
    const int lane = tid & 63;
    const int wv   = tid >> 6;
    const long r0  = (long)blockIdx.x * 64;

    for (int it = 0; it < 32; ++it) {
        int c = it * 256 + tid;
        int row = c >> 7, j = c & 127;
        long gi = (r0 + row) * 1024 + j * 8;
        float tp[8];
        *(uint4*)tp       = *(const uint4*)(y + gi);
        *(uint4*)(tp + 4) = *(const uint4*)(y + gi + 4);
        *(uint4*)(sA + row * 2048 + ((j * 16) ^ ((row & 7) << 4))) = pack8f(tp);
    }
    __syncthreads();

    for (int nt = 0; nt < 8; ++nt) {
        f32x4 acc[4][2] = {};
        for (int kt = 0; kt < 16; ++kt) {
            __syncthreads();
#pragma unroll
            for (int uu = 0; uu < 4; ++uu) {
                int u = uu * 256 + tid;
                int nrow = u >> 3, jc = u & 7;
                u16 e[8];
#pragma unroll
                for (int q = 0; q < 8; ++q)
                    e[q] = f2b(Why[(long)(kt * 64 + jc * 8 + q) * 1024 + nt * 128 + nrow]);
                uint4 v; __builtin_memcpy(&v, e, 16);
                *(uint4*)(sW + nrow * 128 + ((jc * 16) ^ ((nrow & 7) << 4))) = v;
            }
            __syncthreads();
#pragma unroll
            for (int ks = 0; ks < 2; ++ks) {
                int kbA = kt * 128 + ks * 64 + ((lane >> 4) << 4);
                int kbW = ks * 64 + ((lane >> 4) << 4);
#pragma unroll
                for (int cc = 0; cc < 2; ++cc) {
                    int brr = (wv * 2 + cc) * 16 + (lane & 15);
                    bf16x8 bF = *(const bf16x8*)(sW + brr * 128 + (kbW ^ ((brr & 7) << 4)));
#pragma unroll
                    for (int m = 0; m < 4; ++m) {
                        int ar = m * 16 + (lane & 15);
                        bf16x8 aF = *(const bf16x8*)(sA + ar * 2048 + (kbA ^ ((ar & 7) << 4)));
                        acc[m][cc] = __builtin_amdgcn_mfma_f32_16x16x32_bf16(
                            aF, bF, acc[m][cc], 0, 0, 0);
                    }
                }
            }
        }
#pragma unroll
        for (int cc = 0; cc < 2; ++cc) {
            int col = nt * 128 + (wv * 2 + cc) * 16 + (lane & 15);
            float bv = by[col];
#pragma unroll
            for (int m = 0; m < 4; ++m)
#pragma unroll
                for (int q = 0; q < 4; ++q) {
                    long row = r0 + m * 16 + ((lane >> 4) << 2) + q;
                    y[row * 1024 + col] = acc[m][cc][q] + bv;
                }
        }
    }
}

// ---------------------------------------------------------------------------
extern "C" void kernel_launch(void* const* d_in, const int* in_sizes, int n_in,
                              void* d_out, int out_size, void* d_ws,
                              size_t ws_size, hipStream_t stream) {
    const float* input = (const float*)d_in[0];
    const float* Wxz = (const float*)d_in[1];
    const float* Whz = (const float*)d_in[2];
    const float* bz  = (const float*)d_in[3];
    const float* Wxr = (const float*)d_in[4];
    const float* Whr = (const float*)d_in[5];
    const float* br  = (const float*)d_in[6];
    const float* Wxg = (const float*)d_in[7];
    const float* Whg = (const float*)d_in[8];
    const float* bg  = (const float*)d_in[9];
    const float* Why = (const float*)d_in[10];
    const float* by  = (const float*)d_in[11];
    (void)in_sizes; (void)n_in; (void)out_size; (void)ws_size;

    float* yreg   = (float*)d_out;            // [64][512][1024] h1 -> y
    float* hidden = yreg + 33554432;          // [64][2][1024]

    char* ws = (char*)d_ws;
    u32* flags = (u32*)ws;                    //  32768 B [2][4][2][512]
    u16* hb    = (u16*)(ws + 32768);          // 262144 B [2][4][16][1024]
    u16* rb    = (u16*)(ws + 294912);         // 262144 B
    u16* ring  = (u16*)(ws + 557056);         // 1048576 B [8][64][1024]

    hipFuncSetAttribute(reinterpret_cast<const void*>(gru_fused),
                        hipFuncAttributeMaxDynamicSharedMemorySize, SCAN_LDS);
    hipFuncSetAttribute(reinterpret_cast<const void*>(ygemm),
                        hipFuncAttributeMaxDynamicSharedMemorySize, YG_LDS);
    hipMemsetAsync(flags, 0, 32768, stream);

    gru_fused<<<256, 512, SCAN_LDS, stream>>>(
        input, Wxz, Wxr, Wxg, Whz, Whr, Whg, bz, br, bg,
        yreg, hidden, ring, hb, rb, flags);
    ygemm<<<512, 256, YG_LDS, stream>>>(Why, by, yreg);
}

// Round 16
// 11690.279 us; speedup vs baseline: 1.2089x; 1.2089x over previous
//
#include <hip/hip_runtime.h>
#include <cstdint>

using u16 = unsigned short;
using u32 = unsigned int;
using u64 = unsigned long long;

typedef __bf16 bf16x8 __attribute__((ext_vector_type(8)));
typedef float  f32x4  __attribute__((ext_vector_type(4)));
typedef unsigned int u32x4 __attribute__((ext_vector_type(4)));

#define WPITCH 2064
#define SCAN_LDS 124160
#define YG_LDS   147456
#define POLL_BOUND 32768

__device__ __forceinline__ float b2f(u16 u) {
    u32 i = ((u32)u) << 16; float f; __builtin_memcpy(&f, &i, 4); return f;
}
__device__ __forceinline__ u16 f2b(float f) {
    u32 i; __builtin_memcpy(&i, &f, 4);
    u32 r = (i + 0x7FFFu + ((i >> 16) & 1u)) >> 16; return (u16)r;
}
__device__ __forceinline__ uint4 pack8f(const float* f) {
    u16 t[8];
#pragma unroll
    for (int j = 0; j < 8; ++j) t[j] = f2b(f[j]);
    uint4 r; __builtin_memcpy(&r, t, 16); return r;
}

// ---------------------------------------------------------------------------
// Fused 2-layer persistent GRU scan, 512 steps, layer-pipelined (skew 4..8).
// 256 WGs x 512 thr (1 WG/CU): blockIdx>>7 = layer; per layer 4 groups x 32
// WGs; group owns 16 batches, WG owns 32 H-cols. Recurrent weights in VGPRs.
// h0 flows layer0 -> layer1 through a depth-8 bf16 ring in ws (sc0 sc1).
// x-projection: 2-step windows, 8 K-tiles/step, staged around the flag waits.
// Sync: sc0 sc1 stores/loads + vmcnt-ordered per-WG epoch flags.
// This is the best-measured schedule (R11: 11.25 ms kernel).
// ---------------------------------------------------------------------------
__global__ __launch_bounds__(512) void gru_fused(
    const float* __restrict__ xin,   // input [64][512][1024] f32
    const float* __restrict__ Wxz, const float* __restrict__ Wxr,
    const float* __restrict__ Wxg,
    const float* __restrict__ Whz, const float* __restrict__ Whr,
    const float* __restrict__ Whg,
    const float* __restrict__ bzp, const float* __restrict__ brp,
    const float* __restrict__ bgp,
    float* __restrict__ hout,        // d_out y-region: h1 rows [b][t][1024]
    float* __restrict__ hidden,      // d_out tail [b][2][1024]
    u16* __restrict__ ring,          // [8][64][1024] bf16 (h0 pipe)
    u16* __restrict__ hb,            // [2][4][16][1024] bf16 (h exch, L1 uses)
    u16* __restrict__ rb,            // [2][4][16][1024] bf16 (rh exch)
    u32* __restrict__ flags)         // [2][4][2 phase][512] u32
{
    extern __shared__ char sm[];
    char*  hs    = sm;                     // 33024: h/rh stage, 16 x 2064
    char*  scZ   = sm + 33024;             // 32768: GEMV partials (4 slots)
    char*  xb0   = sm + 65792;             // 16384: x-stage (A 4KB | W 12KB)
    char*  xb1   = sm + 82176;             // 16384
    float* xls   = (float*)(sm + 98560);   // 24576: [2 buf][2 tl][16 b][96]
    u16*   tmp16 = (u16*)(sm + 123136);    // 1024: publish repack [16][32]

    const int tid   = threadIdx.x;
    const int lane  = tid & 63;
    const int wv    = tid >> 6;
    const int layer = blockIdx.x >> 7;
    const int id    = blockIdx.x & 127;
    const int grp   = id >> 5;
    const int w     = id & 31;
    const int bg0   = grp * 16;
    const int n0w   = w * 32;
    const long wbase = (long)layer * 1048576;
    const long bbase = (long)layer * 1024;

    u16* hbG = hb + (layer * 4 + grp) * 16384;   // [16][1024]
    u16* rbG = rb + (layer * 4 + grp) * 16384;
    u32* f_rh   = flags + ((layer * 4 + grp) * 2 + 0) * 512;
    u32* f_h    = flags + ((layer * 4 + grp) * 2 + 1) * 512;
    u32* f_h_l0 = flags + ((0 * 4 + grp) * 2 + 1) * 512;
    u32* f_h_l1 = flags + ((1 * 4 + grp) * 2 + 1) * 512;

    // ---- recurrent weights -> VGPR B-fragments (k-order matches A-read)
    bf16x8 wZ[2][4], wR[2][4], wG[2][4];
#pragma unroll
    for (int nt = 0; nt < 2; ++nt) {
#pragma unroll
        for (int i = 0; i < 4; ++i) {
            const int k0  = wv * 128 + i * 32 + ((lane >> 4) << 3);
            const int col = n0w + nt * 16 + (lane & 15);
            u16 ez[8], er[8], eg[8];
#pragma unroll
            for (int j = 0; j < 8; ++j) {
                long o = wbase + (long)(k0 + j) * 1024 + col;
                ez[j] = f2b(Whz[o]); er[j] = f2b(Whr[o]); eg[j] = f2b(Whg[o]);
            }
            __builtin_memcpy(&wZ[nt][i], ez, 16);
            __builtin_memcpy(&wR[nt][i], er, 16);
            __builtin_memcpy(&wG[nt][i], eg, 16);
        }
    }

    const int b8  = tid >> 5;           // batch 0..15
    const int n32 = tid & 31;           // col 0..31
    const int ntc = n32 >> 4, nnc = n32 & 15;
    const int ls  = ((b8 >> 2) << 4) | nnc;
    const int el  = b8 & 3;
    const float biasZ = bzp[bbase + n0w + n32];
    const float biasR = brp[bbase + n0w + n32];
    const float biasG = bgp[bbase + n0w + n32];

    // ---- x-production helpers -------------------------------------------
    f32x4 aX0 = {0,0,0,0}, aX1 = {0,0,0,0};
    const int mT0 = (wv < 6) ? 0 : 1, nT0 = (wv < 6) ? wv : wv - 6;
    const int mT1 = 1, nT1 = 2 + wv;    // valid wv<4

    auto XLOAD = [&](int kt, int wt0, f32x4& ra, u64& rav, f32x4* rw) {
        int r = tid >> 4, j = tid & 15;     // 32 rows x 16 thr, 4 elems
        if (layer == 0) {
            ra = *(const f32x4*)(xin +
                 ((long)(bg0 + (r & 15)) * 512 + (wt0 + (r >> 4))) * 1024 +
                 kt * 64 + j * 4);
        } else {
            const char* p = (const char*)ring +
                ((long)(((wt0 + (r >> 4)) & 7) * 64 + bg0 + (r & 15)) * 1024 +
                 kt * 64 + j * 4) * 2;
            asm volatile("global_load_dwordx2 %0, %1, off sc0 sc1\n\t"
                         "s_waitcnt vmcnt(0)"
                         : "=v"(rav) : "v"(p) : "memory");
        }
        if (tid >= 128) {   // W slab: 384 units (3 gates x 64 k x 2 half16)
            int u = tid - 128, g3 = u >> 7, rem = u & 127, k = rem >> 1,
                half = rem & 1;
            const float* Wp = (g3 == 0 ? Wxz : (g3 == 1 ? Wxr : Wxg)) + wbase +
                              (long)(kt * 64 + k) * 1024 + n0w + half * 16;
            rw[0] = *(const f32x4*)(Wp);
            rw[1] = *(const f32x4*)(Wp + 4);
            rw[2] = *(const f32x4*)(Wp + 8);
            rw[3] = *(const f32x4*)(Wp + 12);
        }
    };
    auto XSTORE = [&](char* xb, const f32x4& ra, u64 rav, const f32x4* rw) {
        char* sA = xb; char* sW = xb + 4096;
        int r = tid >> 4, j = tid & 15;
        u64 v;
        if (layer == 0) {
            u16 e[4];
#pragma unroll
            for (int q = 0; q < 4; ++q) e[q] = f2b(ra[q]);
            __builtin_memcpy(&v, e, 8);
        } else v = rav;
        *(u64*)(sA + r * 128 + ((j * 8) ^ ((r & 7) << 4))) = v;
        if (tid >= 128) {
            int u = tid - 128, g3 = u >> 7, rem = u & 127, k = rem >> 1,
                half = rem & 1;
#pragma unroll
            for (int c = 0; c < 16; ++c) {
                int row = g3 * 32 + half * 16 + c;
                *(u16*)(sW + row * 128 + ((k * 2) ^ ((row & 7) << 4))) =
                    f2b(rw[c >> 2][c & 3]);
            }
        }
    };
    auto XMFMA = [&](char* xb) {
        char* sA = xb; char* sW = xb + 4096;
#pragma unroll
        for (int ks = 0; ks < 2; ++ks) {
            int kb = ks * 64 + ((lane >> 4) << 4);
            {
                int ar = mT0 * 16 + (lane & 15), br_ = nT0 * 16 + (lane & 15);
                bf16x8 aF = *(const bf16x8*)(sA + ar * 128 + (kb ^ ((ar & 7) << 4)));
                bf16x8 bF = *(const bf16x8*)(sW + br_ * 128 + (kb ^ ((br_ & 7) << 4)));
                aX0 = __builtin_amdgcn_mfma_f32_16x16x32_bf16(aF, bF, aX0, 0, 0, 0);
            }
            if (wv < 4) {
                int ar = mT1 * 16 + (lane & 15), br_ = nT1 * 16 + (lane & 15);
                bf16x8 aF = *(const bf16x8*)(sA + ar * 128 + (kb ^ ((ar & 7) << 4)));
                bf16x8 bF = *(const bf16x8*)(sW + br_ * 128 + (kb ^ ((br_ & 7) << 4)));
                aX1 = __builtin_amdgcn_mfma_f32_16x16x32_bf16(aF, bF, aX1, 0, 0, 0);
            }
        }
    };
    // 4 K-tiles, first one pre-loaded into (ra,rav,rw)
    auto XP4 = [&](int kt0, int wt0, f32x4& ra, u64& rav, f32x4* rw) {
        XSTORE(xb0, ra, rav, rw);
        __syncthreads();
        XMFMA(xb0);
        XLOAD(kt0 + 1, wt0, ra, rav, rw);
        XSTORE(xb1, ra, rav, rw);
        __syncthreads();
        XMFMA(xb1);
        XLOAD(kt0 + 2, wt0, ra, rav, rw);
        XSTORE(xb0, ra, rav, rw);
        __syncthreads();
        XMFMA(xb0);
        XLOAD(kt0 + 3, wt0, ra, rav, rw);
        XSTORE(xb1, ra, rav, rw);
        __syncthreads();
        XMFMA(xb1);
    };
    auto XWRITE = [&](int buf) {
#pragma unroll
        for (int q = 0; q < 4; ++q) {
            int row = mT0 * 16 + ((lane >> 4) << 2) + q;   // tl = mT0, b = row&15
            xls[((buf * 2 + mT0) * 16 + (row & 15)) * 96 + nT0 * 16 + (lane & 15)] = aX0[q];
            if (wv < 4) {
                int row1 = 16 + ((lane >> 4) << 2) + q;
                xls[((buf * 2 + 1) * 16 + (row1 & 15)) * 96 + nT1 * 16 + (lane & 15)] = aX1[q];
            }
        }
        aX0 = (f32x4){0,0,0,0}; aX1 = (f32x4){0,0,0,0};
    };
    // ---- exchange helpers (all sc0 sc1) ---------------------------------
    auto STAGE32 = [&](const char* src) {   // 32KB [16][1024]bf16 -> hs
        u32x4 a0, a1, a2, a3;
        const char* p = src + tid * 16;
        asm volatile(
            "global_load_dwordx4 %0, %4, off sc0 sc1\n\t"
            "global_load_dwordx4 %1, %5, off sc0 sc1\n\t"
            "global_load_dwordx4 %2, %6, off sc0 sc1\n\t"
            "global_load_dwordx4 %3, %7, off sc0 sc1\n\t"
            "s_waitcnt vmcnt(0)"
            : "=&v"(a0), "=&v"(a1), "=&v"(a2), "=&v"(a3)
            : "v"(p), "v"(p + 8192), "v"(p + 16384), "v"(p + 24576)
            : "memory");
        u32x4 a[4] = {a0, a1, a2, a3};
#pragma unroll
        for (int u = 0; u < 4; ++u) {
            int idx = u * 512 + tid;
            *(u32x4*)(hs + (idx >> 7) * WPITCH +
                      (((idx & 127) * 16) ^ (((idx >> 7) & 7) << 4))) = a[u];
        }
    };
    auto PUBLISH = [&](char* dst) {   // [16][1024]bf16 slice from tmp16
        if (tid < 64) {
            int b = tid >> 2, q = tid & 3;
            u16 e[8];
#pragma unroll
            for (int j = 0; j < 8; ++j) e[j] = tmp16[b * 32 + q * 8 + j];
            u32x4 v; __builtin_memcpy(&v, e, 16);
            char* p = dst + b * 2048 + n0w * 2 + q * 16;
            asm volatile("global_store_dwordx4 %0, %1, off sc0 sc1"
                         :: "v"(p), "v"(v) : "memory");
        }
    };
    auto FLAGREL = [&](u32* fp, u32 tgtv) {
        if (tid == 0)
            asm volatile("s_waitcnt vmcnt(0)\n\t"
                         "global_store_dword %0, %1, off sc0 sc1"
                         :: "v"(fp), "v"(tgtv) : "memory");
    };
    auto FLAGWAIT = [&](const u32* fpbase, u32 tgtv) {
        if (tid < 32) {
            const u32* fp = fpbase + tid * 16;
            u32 v; int itc = 0;
            for (;;) {
                asm volatile("global_load_dword %0, %1, off sc0 sc1\n\t"
                             "s_waitcnt vmcnt(0)"
                             : "=v"(v) : "v"(fp) : "memory");
                if (v >= tgtv) break;
                if (++itc > POLL_BOUND) break;   // fail loud, never hang
                __builtin_amdgcn_s_sleep(1);
            }
        }
        __builtin_amdgcn_sched_barrier(0);
        __syncthreads();
    };

    // ---- prologue: produce x window [0,1] into xls buf 0
    {
        if (layer == 1) FLAGWAIT(f_h_l0, 2);
        f32x4 ra; u64 rav = 0; f32x4 rw[4];
        for (int kt = 0; kt < 16; kt += 4) {
            XLOAD(kt, 0, ra, rav, rw);
            XP4(kt, 0, ra, rav, rw);
        }
        __syncthreads();
        XWRITE(0);
        __syncthreads();
    }

    float h_own = 0.f;
    for (int tc = 0; tc < 512; ++tc) {
        const bool prod = (tc < 510);
        const int wt0 = (tc & ~1) + 2;
        const int kb8 = (tc & 1) * 8;
        const int buf = (tc >> 1) & 1;
        const int tl  = tc & 1;

        if (layer == 1 && (tc & 1) == 0 && prod)
            FLAGWAIT(f_h_l0, tc + 4);           // window [tc+2,tc+3] readable

        f32x4 ra; u64 rav = 0; f32x4 rw[4];
        if (prod) XLOAD(kb8 + 0, wt0, ra, rav, rw);

        // ---- h(t-1) wait + stage
        if (tc == 0) {
            __syncthreads();
#pragma unroll
            for (int u = 0; u < 4; ++u) {
                int idx = u * 512 + tid;
                *(u32x4*)(hs + (idx >> 7) * WPITCH +
                          (((idx & 127) * 16) ^ (((idx >> 7) & 7) << 4))) =
                    (u32x4){0, 0, 0, 0};
            }
        } else {
            FLAGWAIT(f_h, (u32)tc);
            if (layer == 0)
                STAGE32((const char*)ring + (((tc - 1) & 7) * 64 + bg0) * 2048);
            else
                STAGE32((const char*)hbG);
        }
        __syncthreads();

        if (prod) XP4(kb8 + 0, wt0, ra, rav, rw);

        // ---- z,r GEMV
        {
            f32x4 aZ0 = {0,0,0,0}, aZ1 = {0,0,0,0};
            f32x4 aR0 = {0,0,0,0}, aR1 = {0,0,0,0};
#pragma unroll
            for (int i = 0; i < 4; ++i) {
                int kby = wv * 256 + i * 64 + ((lane >> 4) << 4);
                int ar = lane & 15;
                bf16x8 aF = *(const bf16x8*)(hs + ar * WPITCH + (kby ^ ((ar & 7) << 4)));
                aZ0 = __builtin_amdgcn_mfma_f32_16x16x32_bf16(aF, wZ[0][i], aZ0, 0, 0, 0);
                aZ1 = __builtin_amdgcn_mfma_f32_16x16x32_bf16(aF, wZ[1][i], aZ1, 0, 0, 0);
                aR0 = __builtin_amdgcn_mfma_f32_16x16x32_bf16(aF, wR[0][i], aR0, 0, 0, 0);
                aR1 = __builtin_amdgcn_mfma_f32_16x16x32_bf16(aF, wR[1][i], aR1, 0, 0, 0);
            }
            *(f32x4*)(scZ + ((0 * 8 + wv) * 64 + lane) * 16) = aZ0;
            *(f32x4*)(scZ + ((1 * 8 + wv) * 64 + lane) * 16) = aZ1;
            *(f32x4*)(scZ + ((2 * 8 + wv) * 64 + lane) * 16) = aR0;
            *(f32x4*)(scZ + ((3 * 8 + wv) * 64 + lane) * 16) = aR1;
        }
        __syncthreads();

        // ---- z,r reduce (each thread owns (b8,n32) for both gates)
        float zval;
        {
            float sz = 0.f, sr = 0.f;
#pragma unroll
            for (int ww = 0; ww < 8; ++ww) {
                sz += *(const float*)(scZ + (((ntc)     * 8 + ww) * 64 + ls) * 16 + el * 4);
                sr += *(const float*)(scZ + (((2 + ntc) * 8 + ww) * 64 + ls) * 16 + el * 4);
            }
            const float* xrow = xls + ((buf * 2 + tl) * 16 + b8) * 96;
            sz += xrow[n32] + biasZ;
            sr += xrow[32 + n32] + biasR;
            zval = 1.f / (1.f + __expf(-sz));
            float rv = 1.f / (1.f + __expf(-sr));
            tmp16[b8 * 32 + n32] = f2b(rv * h_own);
        }
        __syncthreads();

        PUBLISH((char*)rbG);
        FLAGREL(f_rh + w * 16, (u32)(tc + 1));

        if (prod) XLOAD(kb8 + 4, wt0, ra, rav, rw);

        FLAGWAIT(f_rh, (u32)(tc + 1));
        STAGE32((const char*)rbG);
        __syncthreads();

        if (prod) XP4(kb8 + 4, wt0, ra, rav, rw);

        // ---- g GEMV
        {
            f32x4 aG0 = {0,0,0,0}, aG1 = {0,0,0,0};
#pragma unroll
            for (int i = 0; i < 4; ++i) {
                int kby = wv * 256 + i * 64 + ((lane >> 4) << 4);
                int ar = lane & 15;
                bf16x8 aF = *(const bf16x8*)(hs + ar * WPITCH + (kby ^ ((ar & 7) << 4)));
                aG0 = __builtin_amdgcn_mfma_f32_16x16x32_bf16(aF, wG[0][i], aG0, 0, 0, 0);
                aG1 = __builtin_amdgcn_mfma_f32_16x16x32_bf16(aF, wG[1][i], aG1, 0, 0, 0);
            }
            *(f32x4*)(scZ + ((0 * 8 + wv) * 64 + lane) * 16) = aG0;
            *(f32x4*)(scZ + ((1 * 8 + wv) * 64 + lane) * 16) = aG1;
        }
        __syncthreads();

        // ---- g reduce + h update
        {
            float sg = 0.f;
#pragma unroll
            for (int ww = 0; ww < 8; ++ww)
                sg += *(const float*)(scZ + ((ntc * 8 + ww) * 64 + ls) * 16 + el * 4);
            sg += xls[((buf * 2 + tl) * 16 + b8) * 96 + 64 + n32] + biasG;
            float e  = __expf(-2.f * sg);
            float gt = 2.f / (1.f + e) - 1.f;
            float hn = zval * h_own + (1.f - zval) * gt;
            h_own = hn;
            tmp16[b8 * 32 + n32] = f2b(hn);
            if (layer == 1)
                hout[((long)(bg0 + b8) * 512 + tc) * 1024 + n0w + n32] = hn;
            if (tc == 511)
                hidden[(long)(bg0 + b8) * 2048 + layer * 1024 + n0w + n32] = hn;
        }
        __syncthreads();

        PUBLISH(layer == 0
                    ? (char*)ring + (((tc & 7) * 64 + bg0) * 2048)
                    : (char*)hbG);
        FLAGREL(f_h + w * 16, (u32)(tc + 1));

        if (tl == 1 && prod) {
            __syncthreads();
            XWRITE(buf ^ 1);
        }
    }
}

// ---------------------------------------------------------------------------
// In-place output projection: y = h1 @ Why + by over h1 rows in d_out.
// ---------------------------------------------------------------------------
__global__ __launch_bounds__(256) void ygemm(const float* __restrict__ Why,
                                             const float* __restrict__ by,
                                             float* __restrict__ y)
{
    extern __shared__ char sm[];
    char* sA = sm;            // 64 rows x 2048B (bf16 k=1024)
    char* sW = sm + 131072;   // 128 n-rows x 128B

    const int tid  = threadIdx.x;
    const int lane = tid & 63;
    const int wv   = tid >> 6;
    const long r0  = (long)blockIdx.x * 64;

    for (int it = 0; it < 32; ++it) {
        int c = it * 256 + tid;
        int row = c >> 7, j = c & 127;
        long gi = (r0 + row) * 1024 + j * 8;
        float tp[8];
        *(uint4*)tp       = *(const uint4*)(y + gi);
        *(uint4*)(tp + 4) = *(const uint4*)(y + gi + 4);
        *(uint4*)(sA + row * 2048 + ((j * 16) ^ ((row & 7) << 4))) = pack8f(tp);
    }
    __syncthreads();

    for (int nt = 0; nt < 8; ++nt) {
        f32x4 acc[4][2] = {};
        for (int kt = 0; kt < 16; ++kt) {
            __syncthreads();
#pragma unroll
            for (int uu = 0; uu < 4; ++uu) {
                int u = uu * 256 + tid;
                int nrow = u >> 3, jc = u & 7;
                u16 e[8];
#pragma unroll
                for (int q = 0; q < 8; ++q)
                    e[q] = f2b(Why[(long)(kt * 64 + jc * 8 + q) * 1024 + nt * 128 + nrow]);
                uint4 v; __builtin_memcpy(&v, e, 16);
                *(uint4*)(sW + nrow * 128 + ((jc * 16) ^ ((nrow & 7) << 4))) = v;
            }
            __syncthreads();
#pragma unroll
            for (int ks = 0; ks < 2; ++ks) {
                int kbA = kt * 128 + ks * 64 + ((lane >> 4) << 4);
                int kbW = ks * 64 + ((lane >> 4) << 4);
#pragma unroll
                for (int cc = 0; cc < 2; ++cc) {
                    int brr = (wv * 2 + cc) * 16 + (lane & 15);
                    bf16x8 bF = *(const bf16x8*)(sW + brr * 128 + (kbW ^ ((brr & 7) << 4)));
#pragma unroll
                    for (int m = 0; m < 4; ++m) {
                        int ar = m * 16 + (lane & 15);
                        bf16x8 aF = *(const bf16x8*)(sA + ar * 2048 + (kbA ^ ((ar & 7) << 4)));
                        acc[m][cc] = __builtin_amdgcn_mfma_f32_16x16x32_bf16(
                            aF, bF, acc[m][cc], 0, 0, 0);
                    }
                }
            }
        }
#pragma unroll
        for (int cc = 0; cc < 2; ++cc) {
            int col = nt * 128 + (wv * 2 + cc) * 16 + (lane & 15);
            float bv = by[col];
#pragma unroll
            for (int m = 0; m < 4; ++m)
#pragma unroll
                for (int q = 0; q < 4; ++q) {
                    long row = r0 + m * 16 + ((lane >> 4) << 2) + q;
                    y[row * 1024 + col] = acc[m][cc][q] + bv;
                }
        }
    }
}

// ---------------------------------------------------------------------------
extern "C" void kernel_launch(void* const* d_in, const int* in_sizes, int n_in,
                              void* d_out, int out_size, void* d_ws,
                              size_t ws_size, hipStream_t stream) {
    const float* input = (const float*)d_in[0];
    const float* Wxz = (const float*)d_in[1];
    const float* Whz = (const float*)d_in[2];
    const float* bz  = (const float*)d_in[3];
    const float* Wxr = (const float*)d_in[4];
    const float* Whr = (const float*)d_in[5];
    const float* br  = (const float*)d_in[6];
    const float* Wxg = (const float*)d_in[7];
    const float* Whg = (const float*)d_in[8];
    const float* bg  = (const float*)d_in[9];
    const float* Why = (const float*)d_in[10];
    const float* by  = (const float*)d_in[11];
    (void)in_sizes; (void)n_in; (void)out_size; (void)ws_size;

    float* yreg   = (float*)d_out;            // [64][512][1024] h1 -> y
    float* hidden = yreg + 33554432;          // [64][2][1024]

    char* ws = (char*)d_ws;
    u32* flags = (u32*)ws;                    //  32768 B [2][4][2][512]
    u16* hb    = (u16*)(ws + 32768);          // 262144 B [2][4][16][1024]
    u16* rb    = (u16*)(ws + 294912);         // 262144 B
    u16* ring  = (u16*)(ws + 557056);         // 1048576 B [8][64][1024]

    hipFuncSetAttribute(reinterpret_cast<const void*>(gru_fused),
                        hipFuncAttributeMaxDynamicSharedMemorySize, SCAN_LDS);
    hipFuncSetAttribute(reinterpret_cast<const void*>(ygemm),
                        hipFuncAttributeMaxDynamicSharedMemorySize, YG_LDS);
    hipMemsetAsync(flags, 0, 32768, stream);

    gru_fused<<<256, 512, SCAN_LDS, stream>>>(
        input, Wxz, Wxr, Wxg, Whz, Whr, Whg, bz, br, bg,
        yreg, hidden, ring, hb, rb, flags);
    ygemm<<<512, 256, YG_LDS, stream>>>(Why, by, yreg);
}